// Round 5
// baseline (202.729 us; speedup 1.0000x reference)
//
#include <hip/hip_runtime.h>
#include <math.h>

// CapsuleLayer dynamic routing, fused. R11: T=1024, MB=2, og8 packed W.
// R10 post-mortem: zero spill confirmed (WRITE 0.18 MB), 75 us, VALUBusy 34%,
// L2 W-stream 1.5 GB @ ~20 TB/s — neither txn-rate nor byte ceiling saturated;
// the robust lever is halving W BYTES again. R9's lesson: MB=2 spills iff
// pri_floats = NR*OC*MB/T > 36. T=1024 restores 36 floats/thread (float2[9]
// per batch, og spans 8 lanes) => R10's exact register economy + half the W
// traffic (755 MB). Occupancy quantizes to 1 block/CU = 4 waves/EU (50%).
// Packed layout rev: Wp2[((c*9+p)*8+k)*1024 + t] = W2[c][(t>>3)+128p][k][t&7]
// — wave load = 64 lanes x 8 B = 512 B contiguous, full 128 B lines.

#define NBATCH 256
#define NC 10
#define NR 1152
#define IC 8
#define OC 16
#define NITER 3
#define T 1024
#define MB 2
#define RPT 9    // NR / 128 r-values per thread per batch
#define WP_F2 (NC * RPT * 8 * T)   // 737280 float2 = 5.9 MB packed W

// ---------------------------------------------------------------------------
// Repack W[c][r][i][o] (float2 granularity: idx ((c*NR+r)*IC+i)*8+og) into
// wave-linear Wp2[((c*9+p)*8+k)*1024 + t] = W2[c][(t>>3)+128p][k][og=t&7].
// ---------------------------------------------------------------------------
__global__ __launch_bounds__(256)
void repack_w(const float2* __restrict__ W2, float2* __restrict__ Wp) {
    int j = blockIdx.x * 256 + threadIdx.x;      // ((c*9+p)*8+k)*1024 + t
    int t  = j & 1023;
    int pk = (j >> 10) % 72;
    int c  = (j >> 10) / 72;
    int p  = pk >> 3, k = pk & 7;
    int r  = (t >> 3) + (p << 7);
    int og = t & 7;
    Wp[j] = W2[(((size_t)c * NR + r) * IC + k) * 8 + og];
}

__device__ __forceinline__ float wave_sum(float v) {
#pragma unroll
    for (int m = 1; m <= 32; m <<= 1) v += __shfl_xor(v, m, 64);
    return v;
}
__device__ __forceinline__ float wave_max(float v) {
#pragma unroll
    for (int m = 1; m <= 32; m <<= 1) v = fmaxf(v, __shfl_xor(v, m, 64));
    return v;
}

template <bool PACKED>
__global__ __launch_bounds__(T)
__attribute__((amdgpu_waves_per_eu(4, 4)))   // 16-wave block => 4/EU, 128-reg budget
void caps_route(
    const float* __restrict__ x,   // [B, NR, IC]
    const float2* __restrict__ Wg, // PACKED ? Wp : W (as float2)
    float* __restrict__ out)       // [B, NC, OC]
{
    __shared__ float logit0[NR];     // 4608 B
    __shared__ float logit1[NR];     // 4608 B
    __shared__ float red[2 * 256];   // per batch: 16 waves x 16 outputs
    __shared__ float sred[2 * 16];   // per batch: 16 wave-stats
    __shared__ float vout[2 * OC];

    const int t    = threadIdx.x;
    const int og   = t & 7;        // o-pair (o = og*2+j)
    const int rr   = t >> 3;       // 0..127
    const int lane = t & 63;
    const int wid  = t >> 6;       // 0..15

    const int c  = blockIdx.x >> 7;     // c-major: 128 consecutive blocks share W[c]
    const int bp = blockIdx.x & 127;
    const int b0 = bp * 2;              // b1 = b0+1

    // ---------------- Phase A: pri{0,1}[p] for r=rr+128p, o-pair og --------
    float2 pri0[RPT], pri1[RPT];
    const float4* __restrict__ xg0 = (const float4*)(x + (size_t)b0 * (NR * IC));
    const float4* __restrict__ xg1 = xg0 + NR * 2;

    if (PACKED) {
        const float2* __restrict__ wp = Wg + (size_t)c * (RPT * 8 * T) + t;
#pragma unroll
        for (int p = 0; p < RPT; ++p) {
            const int r = rr + (p << 7);
            float4 xa0 = xg0[2 * r], xc0 = xg0[2 * r + 1];  // 8-lane broadcast
            float4 xa1 = xg1[2 * r], xc1 = xg1[2 * r + 1];
            float xv0[8] = {xa0.x, xa0.y, xa0.z, xa0.w, xc0.x, xc0.y, xc0.z, xc0.w};
            float xv1[8] = {xa1.x, xa1.y, xa1.z, xa1.w, xc1.x, xc1.y, xc1.z, xc1.w};
            float2 a0 = make_float2(0.f, 0.f);
            float2 a1 = make_float2(0.f, 0.f);
#pragma unroll
            for (int k = 0; k < 8; ++k) {
                float2 w = wp[(p * 8 + k) * T];   // 512 B contiguous per wave
                a0.x = fmaf(xv0[k], w.x, a0.x); a1.x = fmaf(xv1[k], w.x, a1.x);
                a0.y = fmaf(xv0[k], w.y, a0.y); a1.y = fmaf(xv1[k], w.y, a1.y);
            }
            pri0[p] = a0;
            pri1[p] = a1;
        }
    } else {
        const float2* __restrict__ wb = Wg + (size_t)c * (NR * IC * 8);
#pragma unroll
        for (int p = 0; p < RPT; ++p) {
            const int r = rr + (p << 7);
            float4 xa0 = xg0[2 * r], xc0 = xg0[2 * r + 1];
            float4 xa1 = xg1[2 * r], xc1 = xg1[2 * r + 1];
            float xv0[8] = {xa0.x, xa0.y, xa0.z, xa0.w, xc0.x, xc0.y, xc0.z, xc0.w};
            float xv1[8] = {xa1.x, xa1.y, xa1.z, xa1.w, xc1.x, xc1.y, xc1.z, xc1.w};
            float2 a0 = make_float2(0.f, 0.f);
            float2 a1 = make_float2(0.f, 0.f);
#pragma unroll
            for (int k = 0; k < 8; ++k) {
                float2 w = wb[((size_t)r * IC + k) * 8 + og];
                a0.x = fmaf(xv0[k], w.x, a0.x); a1.x = fmaf(xv1[k], w.x, a1.x);
                a0.y = fmaf(xv0[k], w.y, a0.y); a1.y = fmaf(xv1[k], w.y, a1.y);
            }
            pri0[p] = a0;
            pri1[p] = a1;
        }
    }

    // ---------------- Phase B: 3 routing iterations -------------------------
    for (int it = 0; it < NITER; ++it) {
        const bool uni = (it == 0);  // softmax of zeros = uniform
        float m0 = 0.f, m1 = 0.f, invd0 = 0.f, invd1 = 0.f;
        if (!uni) {
            float lm0 = -3.4e38f, lm1 = -3.4e38f;
#pragma unroll
            for (int k = 0; k < 2; ++k) {
                int r = t + (k << 10);
                if (r < NR) {
                    lm0 = fmaxf(lm0, logit0[r]);
                    lm1 = fmaxf(lm1, logit1[r]);
                }
            }
            lm0 = wave_max(lm0); lm1 = wave_max(lm1);
            if (lane == 0) { sred[wid] = lm0; sred[16 + wid] = lm1; }
            __syncthreads();
            m0 = sred[0]; m1 = sred[16];
#pragma unroll
            for (int w = 1; w < 16; ++w) {
                m0 = fmaxf(m0, sred[w]); m1 = fmaxf(m1, sred[16 + w]);
            }
            float ls0 = 0.f, ls1 = 0.f;
#pragma unroll
            for (int k = 0; k < 2; ++k) {
                int r = t + (k << 10);
                if (r < NR) {
                    ls0 += __expf(logit0[r] - m0);
                    ls1 += __expf(logit1[r] - m1);
                }
            }
            ls0 = wave_sum(ls0); ls1 = wave_sum(ls1);
            __syncthreads();             // m reads of sred done before rewrite
            if (lane == 0) { sred[wid] = ls0; sred[16 + wid] = ls1; }
            __syncthreads();
            float d0 = 0.f, d1 = 0.f;
#pragma unroll
            for (int w = 0; w < 16; ++w) { d0 += sred[w]; d1 += sred[16 + w]; }
            invd0 = 1.f / d0; invd1 = 1.f / d1;
        }

        // s[o] partials, both batches
        float2 s0 = make_float2(0.f, 0.f);
        float2 s1 = make_float2(0.f, 0.f);
#pragma unroll
        for (int k = 0; k < RPT; ++k) {
            float w0 = 1.0f, w1 = 1.0f;
            if (!uni) {
                const int r = rr + (k << 7);
                w0 = __expf(logit0[r] - m0);
                w1 = __expf(logit1[r] - m1);
            }
            s0.x = fmaf(w0, pri0[k].x, s0.x); s1.x = fmaf(w1, pri1[k].x, s1.x);
            s0.y = fmaf(w0, pri0[k].y, s0.y); s1.y = fmaf(w1, pri1[k].y, s1.y);
        }
        // reduce over the 8 rr slots (same og) within each wave (lane bits 3..5)
#pragma unroll
        for (int msk = 8; msk <= 32; msk <<= 1) {
            s0.x += __shfl_xor(s0.x, msk, 64); s1.x += __shfl_xor(s1.x, msk, 64);
            s0.y += __shfl_xor(s0.y, msk, 64); s1.y += __shfl_xor(s1.y, msk, 64);
        }
        __syncthreads();                 // prior-iter red reads done
        if (lane < 8) {
            ((float2*)red)[wid * 8 + og]         = s0; // red[wid*16 + og*2 +{0,1}]
            ((float2*)(red + 256))[wid * 8 + og] = s1;
        }
        __syncthreads();

        if (t < 2 * OC) {                // t<16: batch0; 16<=t<32: batch1
            const int bsel = t >> 4, o = t & 15;
            float s = 0.f;
#pragma unroll
            for (int w = 0; w < 16; ++w) s += red[bsel * 256 + w * 16 + o];
            s *= uni ? (1.0f / 1152.0f) : (bsel ? invd1 : invd0);
            float sq = s * s;
#pragma unroll
            for (int msk = 1; msk <= 8; msk <<= 1) sq += __shfl_xor(sq, msk, 64);
            float v = s * (sqrtf(sq) / (1.0f + sq)); // squash
            if (it == NITER - 1) out[((size_t)(b0 + bsel) * NC + c) * OC + o] = v;
            else vout[t] = v;
        }
        __syncthreads();

        if (it < NITER - 1) {
            // logit[r] += sum_o pri[r][o]*v[o]
            float2 v0 = ((const float2*)vout)[og];
            float2 v1 = ((const float2*)(vout + OC))[og];
#pragma unroll
            for (int k = 0; k < RPT; ++k) {
                const int r = rr + (k << 7);
                float d0 = pri0[k].x * v0.x + pri0[k].y * v0.y;
                float d1 = pri1[k].x * v1.x + pri1[k].y * v1.y;
                d0 += __shfl_xor(d0, 1, 64); d1 += __shfl_xor(d1, 1, 64);
                d0 += __shfl_xor(d0, 2, 64); d1 += __shfl_xor(d1, 2, 64);
                d0 += __shfl_xor(d0, 4, 64); d1 += __shfl_xor(d1, 4, 64);
                if (og == 0) {
                    if (it == 0) { logit0[r] = d0; logit1[r] = d1; }
                    else         { logit0[r] += d0; logit1[r] += d1; }
                }
            }
            __syncthreads();
        }
    }
}

extern "C" void kernel_launch(void* const* d_in, const int* in_sizes, int n_in,
                              void* d_out, int out_size, void* d_ws, size_t ws_size,
                              hipStream_t stream) {
    const float* x = (const float*)d_in[0];
    const float* W = (const float*)d_in[1];
    float* out = (float*)d_out;
    const size_t wp_bytes = (size_t)WP_F2 * sizeof(float2);  // 5,898,240 B
    if (d_ws != nullptr && ws_size >= wp_bytes) {
        repack_w<<<dim3(WP_F2 / 256), dim3(256), 0, stream>>>(
            (const float2*)W, (float2*)d_ws);
        caps_route<true><<<dim3(NC * (NBATCH / MB)), dim3(T), 0, stream>>>(
            x, (const float2*)d_ws, out);
    } else {
        caps_route<false><<<dim3(NC * (NBATCH / MB)), dim3(T), 0, stream>>>(
            x, (const float2*)W, out);
    }
}